// Round 1
// baseline (2114.395 us; speedup 1.0000x reference)
//
#include <hip/hip_runtime.h>

#define N_NODES 100000
#define N_EDGES 1600000
#define IN_SIZE 512
#define HID_SIZE 256
#define OUT_SIZE 40
#define K_STEPS 10
#define ALPHA 0.1f

#define SCAN_B 2048   // 256 threads * 8 elems
#define SCAN_NB ((N_NODES + SCAN_B - 1) / SCAN_B)   // 49

// ---------------- degree histogram ----------------
__global__ __launch_bounds__(256) void degrees_kern(const int* __restrict__ src,
                                                    const int* __restrict__ dst,
                                                    int* __restrict__ dego,
                                                    int* __restrict__ degi) {
    int i = blockIdx.x * 256 + threadIdx.x;
    if (i < N_EDGES) {
        atomicAdd(&dego[src[i]], 1);
        atomicAdd(&degi[dst[i]], 1);
    }
}

// ---------------- norms ----------------
__global__ __launch_bounds__(256) void norms_kern(const int* __restrict__ dego,
                                                  const int* __restrict__ degi,
                                                  float* __restrict__ nsrc,
                                                  float* __restrict__ ndst) {
    int i = blockIdx.x * 256 + threadIdx.x;
    if (i < N_NODES) {
        nsrc[i] = 1.0f / sqrtf((float)max(dego[i], 1));
        ndst[i] = 1.0f / sqrtf((float)max(degi[i], 1));
    }
}

// ---------------- scan (exclusive prefix over deg_in -> row_ptr) ----------------
__global__ __launch_bounds__(256) void scan_block_sums(const int* __restrict__ deg,
                                                       int* __restrict__ bsum) {
    __shared__ int s[256];
    int t = threadIdx.x, b = blockIdx.x;
    int base = b * SCAN_B + t * 8;
    int v = 0;
#pragma unroll
    for (int u = 0; u < 8; ++u) { int i = base + u; if (i < N_NODES) v += deg[i]; }
    s[t] = v; __syncthreads();
    for (int off = 128; off > 0; off >>= 1) {
        if (t < off) s[t] += s[t + off];
        __syncthreads();
    }
    if (t == 0) bsum[b] = s[0];
}

__global__ void scan_offsets(const int* __restrict__ bsum, int* __restrict__ boff) {
    if (threadIdx.x == 0 && blockIdx.x == 0) {
        int run = 0;
        for (int b = 0; b < SCAN_NB; ++b) { boff[b] = run; run += bsum[b]; }
    }
}

__global__ __launch_bounds__(256) void scan_write(const int* __restrict__ deg,
                                                  const int* __restrict__ boff,
                                                  int* __restrict__ row_ptr,
                                                  int* __restrict__ cursor) {
    __shared__ int s[256];
    int t = threadIdx.x, b = blockIdx.x;
    int base = b * SCAN_B + t * 8;
    int loc[8]; int tot = 0;
#pragma unroll
    for (int u = 0; u < 8; ++u) {
        int i = base + u;
        loc[u] = (i < N_NODES) ? deg[i] : 0;
        tot += loc[u];
    }
    s[t] = tot; __syncthreads();
    // Hillis-Steele inclusive scan over thread sums
    for (int off = 1; off < 256; off <<= 1) {
        int v = (t >= off) ? s[t - off] : 0;
        __syncthreads();
        s[t] += v;
        __syncthreads();
    }
    int run = boff[b] + s[t] - tot;   // exclusive prefix for this thread
#pragma unroll
    for (int u = 0; u < 8; ++u) {
        int i = base + u;
        if (i < N_NODES) {
            row_ptr[i] = run;
            cursor[i]  = run;
            run += loc[u];
            if (i == N_NODES - 1) row_ptr[N_NODES] = run;
        }
    }
}

// ---------------- CSR fill (group edges by dst) ----------------
__global__ __launch_bounds__(256) void fill_csr(const int* __restrict__ src,
                                                const int* __restrict__ dst,
                                                int* __restrict__ cursor,
                                                int* __restrict__ csr) {
    int i = blockIdx.x * 256 + threadIdx.x;
    if (i < N_EDGES) {
        int pos = atomicAdd(&cursor[dst[i]], 1);
        csr[pos] = src[i];
    }
}

// ---------------- fused MLP: h0 = relu(X@W1+b1)@W2+b2 ----------------
// 64 rows/block, 256 threads, per-thread 8x8 fp32 register tile for GEMM1.
// X tile staged TRANSPOSED in LDS so A-operand reads are ds_read_b128.
// H1 kept in LDS (never touches HBM); GEMM2 from LDS (W2 staged transposed).
// LDS layout (floats):
//   [0      .. 10400)  sW2t [40][260]
//   [10432  .. 12480)  sXt  [32][64]        (phase-1 staging, aliased by sH1)
//   [12480  .. 20672)  sW1  [32][256]       (phase-1 staging, aliased by sH1)
//   [10432  .. 27072)  sH1  [64][260]       (phase 2)
#define MLP_LDS_FLOATS 27072
__global__ __launch_bounds__(256) void mlp_fused(const float* __restrict__ X,
                                                 const float* __restrict__ W1,
                                                 const float* __restrict__ b1,
                                                 const float* __restrict__ W2,
                                                 const float* __restrict__ b2,
                                                 float* __restrict__ h0) {
    extern __shared__ float smem[];
    float* sW2t = smem;               // [40][260]
    float* sXt  = smem + 10432;       // [32][64]
    float* sW1f = smem + 12480;       // [32][256]
    float* sH1  = smem + 10432;       // [64][260] (aliases sXt/sW1f after phase 1)

    const int t  = threadIdx.x;
    const int n0 = blockIdx.x * 64;

    // stage W2 transposed: sW2t[o][c] = W2[c][o]
    for (int idx = t; idx < HID_SIZE * OUT_SIZE; idx += 256) {
        int c = idx / OUT_SIZE;
        int o = idx - c * OUT_SIZE;
        sW2t[o * 260 + c] = W2[idx];
    }

    const int rg = t >> 5;          // 0..7  (8 rows each)
    const int cg = t & 31;          // 0..31 (8 cols each)

    float acc[8][8];
#pragma unroll
    for (int i = 0; i < 8; ++i)
#pragma unroll
        for (int j = 0; j < 8; ++j) acc[i][j] = 0.f;

    const int tr  = t >> 2;         // 0..63 row for X staging
    const int tk4 = t & 3;          // covers 8 k's
    const bool rowok = (n0 + tr) < N_NODES;
    const float* Xrow = X + (size_t)(n0 + tr) * IN_SIZE;

    for (int kk = 0; kk < IN_SIZE; kk += 32) {
        __syncthreads();   // previous tile's compute done before overwrite
        // stage X^T: sXt[k][r]
        float4 x0 = make_float4(0.f, 0.f, 0.f, 0.f), x1 = x0;
        if (rowok) {
            x0 = *(const float4*)(Xrow + kk + tk4 * 8);
            x1 = *(const float4*)(Xrow + kk + tk4 * 8 + 4);
        }
        sXt[(tk4 * 8 + 0) * 64 + tr] = x0.x;
        sXt[(tk4 * 8 + 1) * 64 + tr] = x0.y;
        sXt[(tk4 * 8 + 2) * 64 + tr] = x0.z;
        sXt[(tk4 * 8 + 3) * 64 + tr] = x0.w;
        sXt[(tk4 * 8 + 4) * 64 + tr] = x1.x;
        sXt[(tk4 * 8 + 5) * 64 + tr] = x1.y;
        sXt[(tk4 * 8 + 6) * 64 + tr] = x1.z;
        sXt[(tk4 * 8 + 7) * 64 + tr] = x1.w;
        // stage W1 chunk (rows kk..kk+31 are contiguous in global)
        {
            const float4* W1g = (const float4*)(W1 + (size_t)kk * HID_SIZE);
            float4* sW14 = (float4*)sW1f;
#pragma unroll
            for (int u = 0; u < 8; ++u) sW14[t + u * 256] = W1g[t + u * 256];
        }
        __syncthreads();
#pragma unroll 4
        for (int k = 0; k < 32; ++k) {
            const float4 a0 = *(const float4*)&sXt[k * 64 + rg * 8];
            const float4 a1 = *(const float4*)&sXt[k * 64 + rg * 8 + 4];
            const float4 w0 = *(const float4*)&sW1f[k * 256 + cg * 8];
            const float4 w1 = *(const float4*)&sW1f[k * 256 + cg * 8 + 4];
            const float a[8] = {a0.x, a0.y, a0.z, a0.w, a1.x, a1.y, a1.z, a1.w};
            const float w[8] = {w0.x, w0.y, w0.z, w0.w, w1.x, w1.y, w1.z, w1.w};
#pragma unroll
            for (int i = 0; i < 8; ++i)
#pragma unroll
                for (int j = 0; j < 8; ++j)
                    acc[i][j] = fmaf(a[i], w[j], acc[i][j]);
        }
    }
    __syncthreads();   // compute done before sH1 overwrites staging

    // relu(acc + b1) -> sH1
    float bb[8];
#pragma unroll
    for (int j = 0; j < 8; ++j) bb[j] = b1[cg * 8 + j];
#pragma unroll
    for (int i = 0; i < 8; ++i) {
        const int r = rg * 8 + i;
#pragma unroll
        for (int j = 0; j < 8; ++j) {
            float h = acc[i][j] + bb[j];
            sH1[r * 260 + cg * 8 + j] = fmaxf(h, 0.f);
        }
    }
    __syncthreads();

    // phase 2: out[r][o] = sum_c sH1[r][c] * W2[c][o] + b2[o]
    const int r2 = t >> 2;
    const int q  = t & 3;
    const int o0 = q * 10;
    float acc2[10];
#pragma unroll
    for (int m = 0; m < 10; ++m) acc2[m] = b2[o0 + m];
    for (int c = 0; c < HID_SIZE; c += 4) {
        const float4 h4 = *(const float4*)&sH1[r2 * 260 + c];
#pragma unroll
        for (int m = 0; m < 10; ++m) {
            const float4 w4 = *(const float4*)&sW2t[(o0 + m) * 260 + c];
            acc2[m] += h4.x * w4.x + h4.y * w4.y + h4.z * w4.z + h4.w * w4.w;
        }
    }
    if (n0 + r2 < N_NODES) {
        float* dstp = h0 + (size_t)(n0 + r2) * OUT_SIZE + o0;
#pragma unroll
        for (int m = 0; m < 10; ++m) dstp[m] = acc2[m];
    }
}

// ---------------- one APPNP propagation step (pull-based via CSR) ----------------
// one wave per node; lanes = channels (40 active); edge idx+norm broadcast by shfl
__global__ __launch_bounds__(256) void appnp_step(const float* __restrict__ hin,
                                                  const float* __restrict__ h0,
                                                  const int* __restrict__ row_ptr,
                                                  const int* __restrict__ csr,
                                                  const float* __restrict__ nsrc,
                                                  const float* __restrict__ ndst,
                                                  float* __restrict__ hout) {
    const int wave = blockIdx.x * 4 + (threadIdx.x >> 6);
    const int lane = threadIdx.x & 63;
    if (wave >= N_NODES) return;
    const int n = wave;
    const int beg = row_ptr[n];
    const int end = row_ptr[n + 1];
    const int c = lane;
    float acc = 0.f;
    for (int e = beg; e < end; e += 64) {
        const int cnt = min(64, end - e);
        int   myidx = (lane < cnt) ? csr[e + lane] : 0;
        float mynrm = (lane < cnt) ? nsrc[myidx] : 0.f;
        for (int j = 0; j < cnt; ++j) {
            const int   s  = __shfl(myidx, j);
            const float ns = __shfl(mynrm, j);
            if (c < OUT_SIZE) acc = fmaf(hin[(size_t)s * OUT_SIZE + c], ns, acc);
        }
    }
    if (c < OUT_SIZE) {
        const float r = (1.0f - ALPHA) * ndst[n] * acc + ALPHA * h0[(size_t)n * OUT_SIZE + c];
        hout[(size_t)n * OUT_SIZE + c] = r;
    }
}

// ---------------- launcher ----------------
extern "C" void kernel_launch(void* const* d_in, const int* in_sizes, int n_in,
                              void* d_out, int out_size, void* d_ws, size_t ws_size,
                              hipStream_t stream) {
    const float* X  = (const float*)d_in[0];
    const int*   src = (const int*)d_in[1];
    const int*   dst = (const int*)d_in[2];
    const float* W1 = (const float*)d_in[3];
    const float* b1 = (const float*)d_in[4];
    const float* W2 = (const float*)d_in[5];
    const float* b2 = (const float*)d_in[6];
    float* out = (float*)d_out;

    char* ws = (char*)d_ws;
    size_t off = 0;
    auto alloc = [&](size_t bytes) -> void* {
        void* p = ws + off;
        off = (off + bytes + 255) & ~(size_t)255;
        return p;
    };
    float* h0   = (float*)alloc((size_t)N_NODES * OUT_SIZE * 4);
    float* hA   = (float*)alloc((size_t)N_NODES * OUT_SIZE * 4);
    float* hB   = (float*)alloc((size_t)N_NODES * OUT_SIZE * 4);
    float* nsrc = (float*)alloc((size_t)N_NODES * 4);
    float* ndst = (float*)alloc((size_t)N_NODES * 4);
    int* dego   = (int*)alloc((size_t)N_NODES * 4);
    int* degi   = (int*)alloc((size_t)N_NODES * 4);
    int* rowp   = (int*)alloc((size_t)(N_NODES + 1) * 4);
    int* cur    = (int*)alloc((size_t)N_NODES * 4);
    int* csr    = (int*)alloc((size_t)N_EDGES * 4);
    int* bsum   = (int*)alloc((size_t)SCAN_NB * 4);
    int* boff   = (int*)alloc((size_t)SCAN_NB * 4);

    hipMemsetAsync(dego, 0, (size_t)N_NODES * 4, stream);
    hipMemsetAsync(degi, 0, (size_t)N_NODES * 4, stream);

    const int egrid = (N_EDGES + 255) / 256;           // 6250
    const int ngrid = (N_NODES + 255) / 256;           // 391

    degrees_kern<<<egrid, 256, 0, stream>>>(src, dst, dego, degi);
    norms_kern<<<ngrid, 256, 0, stream>>>(dego, degi, nsrc, ndst);
    scan_block_sums<<<SCAN_NB, 256, 0, stream>>>(degi, bsum);
    scan_offsets<<<1, 64, 0, stream>>>(bsum, boff);
    scan_write<<<SCAN_NB, 256, 0, stream>>>(degi, boff, rowp, cur);
    fill_csr<<<egrid, 256, 0, stream>>>(src, dst, cur, csr);

    const int mgrid = (N_NODES + 63) / 64;             // 1563
    mlp_fused<<<mgrid, 256, MLP_LDS_FLOATS * 4, stream>>>(X, W1, b1, W2, b2, h0);

    const float* hin = h0;
    const int sgrid = (N_NODES + 3) / 4;               // 25000
    for (int s = 0; s < K_STEPS; ++s) {
        float* hout = (s == K_STEPS - 1) ? out : ((s & 1) ? hB : hA);
        appnp_step<<<sgrid, 256, 0, stream>>>(hin, h0, rowp, csr, nsrc, ndst, hout);
        hin = hout;
    }
}

// Round 2
// 1496.325 us; speedup vs baseline: 1.4131x; 1.4131x over previous
//
#include <hip/hip_runtime.h>

#define N_NODES 100000
#define N_EDGES 1600000
#define IN_SIZE 512
#define HID_SIZE 256
#define OUT_SIZE 40
#define K_STEPS 10
#define ALPHA 0.1f

#define SCAN_B 2048   // 256 threads * 8 elems
#define SCAN_NB ((N_NODES + SCAN_B - 1) / SCAN_B)   // 49

typedef _Float16 half8 __attribute__((ext_vector_type(8)));
typedef float f32x4 __attribute__((ext_vector_type(4)));

// ---------------- degree histogram ----------------
__global__ __launch_bounds__(256) void degrees_kern(const int* __restrict__ src,
                                                    const int* __restrict__ dst,
                                                    int* __restrict__ dego,
                                                    int* __restrict__ degi) {
    int i = blockIdx.x * 256 + threadIdx.x;
    if (i < N_EDGES) {
        atomicAdd(&dego[src[i]], 1);
        atomicAdd(&degi[dst[i]], 1);
    }
}

// ---------------- norms ----------------
__global__ __launch_bounds__(256) void norms_kern(const int* __restrict__ dego,
                                                  const int* __restrict__ degi,
                                                  float* __restrict__ nsrc,
                                                  float* __restrict__ ndst) {
    int i = blockIdx.x * 256 + threadIdx.x;
    if (i < N_NODES) {
        nsrc[i] = 1.0f / sqrtf((float)max(dego[i], 1));
        ndst[i] = 1.0f / sqrtf((float)max(degi[i], 1));
    }
}

// ---------------- scan (exclusive prefix over deg_in -> row_ptr) ----------------
__global__ __launch_bounds__(256) void scan_block_sums(const int* __restrict__ deg,
                                                       int* __restrict__ bsum) {
    __shared__ int s[256];
    int t = threadIdx.x, b = blockIdx.x;
    int base = b * SCAN_B + t * 8;
    int v = 0;
#pragma unroll
    for (int u = 0; u < 8; ++u) { int i = base + u; if (i < N_NODES) v += deg[i]; }
    s[t] = v; __syncthreads();
    for (int off = 128; off > 0; off >>= 1) {
        if (t < off) s[t] += s[t + off];
        __syncthreads();
    }
    if (t == 0) bsum[b] = s[0];
}

__global__ void scan_offsets(const int* __restrict__ bsum, int* __restrict__ boff) {
    if (threadIdx.x == 0 && blockIdx.x == 0) {
        int run = 0;
        for (int b = 0; b < SCAN_NB; ++b) { boff[b] = run; run += bsum[b]; }
    }
}

__global__ __launch_bounds__(256) void scan_write(const int* __restrict__ deg,
                                                  const int* __restrict__ boff,
                                                  int* __restrict__ row_ptr,
                                                  int* __restrict__ cursor) {
    __shared__ int s[256];
    int t = threadIdx.x, b = blockIdx.x;
    int base = b * SCAN_B + t * 8;
    int loc[8]; int tot = 0;
#pragma unroll
    for (int u = 0; u < 8; ++u) {
        int i = base + u;
        loc[u] = (i < N_NODES) ? deg[i] : 0;
        tot += loc[u];
    }
    s[t] = tot; __syncthreads();
    for (int off = 1; off < 256; off <<= 1) {
        int v = (t >= off) ? s[t - off] : 0;
        __syncthreads();
        s[t] += v;
        __syncthreads();
    }
    int run = boff[b] + s[t] - tot;
#pragma unroll
    for (int u = 0; u < 8; ++u) {
        int i = base + u;
        if (i < N_NODES) {
            row_ptr[i] = run;
            cursor[i]  = run;
            run += loc[u];
            if (i == N_NODES - 1) row_ptr[N_NODES] = run;
        }
    }
}

// ---------------- CSR fill (group edges by dst) ----------------
__global__ __launch_bounds__(256) void fill_csr(const int* __restrict__ src,
                                                const int* __restrict__ dst,
                                                int* __restrict__ cursor,
                                                int* __restrict__ csr) {
    int i = blockIdx.x * 256 + threadIdx.x;
    if (i < N_EDGES) {
        int pos = atomicAdd(&cursor[dst[i]], 1);
        csr[pos] = src[i];
    }
}

// ---------------- prep: W1^T as fp16 [256][512] ----------------
__global__ __launch_bounds__(256) void prep_w1t(const float* __restrict__ W1,
                                                unsigned short* __restrict__ w1t) {
    int idx = blockIdx.x * 256 + threadIdx.x;   // 131072
    if (idx < IN_SIZE * HID_SIZE) {
        int n = idx >> 9;       // 0..255
        int k = idx & 511;      // 0..511
        _Float16 h = (_Float16)W1[(size_t)k * HID_SIZE + n];
        w1t[idx] = *(unsigned short*)&h;
    }
}

// ---------------- GEMM1: h1 = relu(X @ W1 + b1) in fp16 via MFMA ----------------
// BM=128, BN=256 (full), BK=64. 512 threads = 8 waves (2 M x 4 N), per-wave 64x64.
// LDS: A [128][64] fp16 (16KB) + B^T [256][64] fp16 (32KB), XOR-swizzled 16B chunks.
// X converted fp32->fp16 during staging (read once). mfma_f32_16x16x32_f16.
__global__ __launch_bounds__(512) void gemm1_f16(const float* __restrict__ X,
                                                 const unsigned short* __restrict__ w1t,
                                                 const float* __restrict__ b1,
                                                 _Float16* __restrict__ h1) {
    __shared__ __align__(16) _Float16 sA[128 * 64];
    __shared__ __align__(16) _Float16 sB[256 * 64];

    const int t    = threadIdx.x;
    const int lane = t & 63;
    const int w    = t >> 6;        // 0..7
    const int wr   = w >> 2;        // 0..1 : M
    const int wc   = w & 3;         // 0..3 : N
    const int n0   = blockIdx.x * 128;

    f32x4 acc[4][4];
#pragma unroll
    for (int i = 0; i < 4; ++i)
#pragma unroll
        for (int j = 0; j < 4; ++j) acc[i][j] = (f32x4)0.f;

    const int lo = lane & 15;
    const int hi = lane >> 4;
    const int l7 = lane & 7;

    for (int kk = 0; kk < IN_SIZE; kk += 64) {
        __syncthreads();
        // ---- stage A: X[128 rows][kk..kk+63] -> fp16, swizzled ----
#pragma unroll
        for (int i = 0; i < 2; ++i) {
            int id  = t + i * 512;          // 0..1023
            int row = id >> 3;              // 0..127
            int ch  = id & 7;               // 16B chunk (8 halves)
            int gr  = n0 + row;
            float4 x0 = make_float4(0.f, 0.f, 0.f, 0.f), x1 = x0;
            if (gr < N_NODES) {
                const float* p = X + (size_t)gr * IN_SIZE + kk + ch * 8;
                x0 = ((const float4*)p)[0];
                x1 = ((const float4*)p)[1];
            }
            half8 hv;
            hv[0] = (_Float16)x0.x; hv[1] = (_Float16)x0.y;
            hv[2] = (_Float16)x0.z; hv[3] = (_Float16)x0.w;
            hv[4] = (_Float16)x1.x; hv[5] = (_Float16)x1.y;
            hv[6] = (_Float16)x1.z; hv[7] = (_Float16)x1.w;
            *(half8*)&sA[row * 64 + ((ch ^ (row & 7)) << 3)] = hv;
        }
        // ---- stage B: W1^T[256 n][kk..kk+63] fp16, swizzled ----
#pragma unroll
        for (int i = 0; i < 4; ++i) {
            int id = t + i * 512;           // 0..2047
            int n  = id >> 3;               // 0..255
            int ch = id & 7;
            uint4 v = *(const uint4*)(w1t + (size_t)n * IN_SIZE + kk + ch * 8);
            *(uint4*)&sB[n * 64 + ((ch ^ (n & 7)) << 3)] = v;
        }
        __syncthreads();
        // ---- compute: 2 k-slices of 32 ----
#pragma unroll
        for (int s = 0; s < 2; ++s) {
            const int chs = ((s * 4 + hi) ^ l7) << 3;
            half8 af[4], bf[4];
#pragma unroll
            for (int f = 0; f < 4; ++f)
                af[f] = *(const half8*)&sA[(wr * 64 + f * 16 + lo) * 64 + chs];
#pragma unroll
            for (int f = 0; f < 4; ++f)
                bf[f] = *(const half8*)&sB[(wc * 64 + f * 16 + lo) * 64 + chs];
#pragma unroll
            for (int fi = 0; fi < 4; ++fi)
#pragma unroll
                for (int fj = 0; fj < 4; ++fj)
                    acc[fi][fj] = __builtin_amdgcn_mfma_f32_16x16x32_f16(
                        af[fi], bf[fj], acc[fi][fj], 0, 0, 0);
        }
    }

    // ---- epilogue: +b1, relu, fp16 store ----
    float b1v[4];
#pragma unroll
    for (int fj = 0; fj < 4; ++fj) b1v[fj] = b1[wc * 64 + fj * 16 + lo];
#pragma unroll
    for (int fi = 0; fi < 4; ++fi) {
#pragma unroll
        for (int fj = 0; fj < 4; ++fj) {
            const int col = wc * 64 + fj * 16 + lo;
#pragma unroll
            for (int r = 0; r < 4; ++r) {
                int grow = n0 + wr * 64 + fi * 16 + hi * 4 + r;
                if (grow < N_NODES) {
                    float v = acc[fi][fj][r] + b1v[fj];
                    v = fmaxf(v, 0.f);
                    h1[(size_t)grow * HID_SIZE + col] = (_Float16)v;
                }
            }
        }
    }
}

// ---------------- GEMM2: h0 = h1 @ W2 + b2 (fp32 accumulate) ----------------
// 64 rows/block, 256 threads. h1 tile fp16 in LDS, W2^T fp32 in LDS.
__global__ __launch_bounds__(256) void gemm2(const _Float16* __restrict__ h1,
                                             const float* __restrict__ W2,
                                             const float* __restrict__ b2,
                                             float* __restrict__ h0) {
    __shared__ __align__(16) float sW2t[40 * 260];
    __shared__ __align__(16) unsigned short sH[64 * 264];

    const int t  = threadIdx.x;
    const int n0 = blockIdx.x * 64;

    for (int idx = t; idx < HID_SIZE * OUT_SIZE; idx += 256) {
        int c = idx / OUT_SIZE;
        int o = idx - c * OUT_SIZE;
        sW2t[o * 260 + c] = W2[idx];
    }
#pragma unroll
    for (int i = 0; i < 8; ++i) {
        int id  = t + i * 256;          // 0..2047
        int row = id >> 5;              // 0..63
        int ch  = id & 31;              // 16B chunks of 8 halves
        uint4 v = make_uint4(0, 0, 0, 0);
        if (n0 + row < N_NODES)
            v = *(const uint4*)(h1 + (size_t)(n0 + row) * HID_SIZE + ch * 8);
        *(uint4*)&sH[row * 264 + ch * 8] = v;
    }
    __syncthreads();

    const int r2 = t >> 2;
    const int q  = t & 3;
    const int o0 = q * 10;
    float acc2[10];
#pragma unroll
    for (int m = 0; m < 10; ++m) acc2[m] = b2[o0 + m];

    for (int c = 0; c < HID_SIZE; c += 8) {
        uint4 hv = *(const uint4*)&sH[r2 * 264 + c];
        const _Float16* hp = (const _Float16*)&hv;
        float f[8];
#pragma unroll
        for (int j = 0; j < 8; ++j) f[j] = (float)hp[j];
#pragma unroll
        for (int m = 0; m < 10; ++m) {
            const float4 w0 = *(const float4*)&sW2t[(o0 + m) * 260 + c];
            const float4 w1 = *(const float4*)&sW2t[(o0 + m) * 260 + c + 4];
            acc2[m] += f[0] * w0.x + f[1] * w0.y + f[2] * w0.z + f[3] * w0.w
                     + f[4] * w1.x + f[5] * w1.y + f[6] * w1.z + f[7] * w1.w;
        }
    }
    if (n0 + r2 < N_NODES) {
        float* dstp = h0 + (size_t)(n0 + r2) * OUT_SIZE + o0;
#pragma unroll
        for (int m = 0; m < 10; ++m) dstp[m] = acc2[m];
    }
}

// ---------------- one APPNP propagation step (pull-based via CSR) ----------------
__global__ __launch_bounds__(256) void appnp_step(const float* __restrict__ hin,
                                                  const float* __restrict__ h0,
                                                  const int* __restrict__ row_ptr,
                                                  const int* __restrict__ csr,
                                                  const float* __restrict__ nsrc,
                                                  const float* __restrict__ ndst,
                                                  float* __restrict__ hout) {
    const int wave = blockIdx.x * 4 + (threadIdx.x >> 6);
    const int lane = threadIdx.x & 63;
    if (wave >= N_NODES) return;
    const int n = wave;
    const int beg = row_ptr[n];
    const int end = row_ptr[n + 1];
    const int c = lane;
    float acc = 0.f;
    for (int e = beg; e < end; e += 64) {
        const int cnt = min(64, end - e);
        int   myidx = (lane < cnt) ? csr[e + lane] : 0;
        float mynrm = (lane < cnt) ? nsrc[myidx] : 0.f;
        for (int j = 0; j < cnt; ++j) {
            const int   s  = __shfl(myidx, j);
            const float ns = __shfl(mynrm, j);
            if (c < OUT_SIZE) acc = fmaf(hin[(size_t)s * OUT_SIZE + c], ns, acc);
        }
    }
    if (c < OUT_SIZE) {
        const float r = (1.0f - ALPHA) * ndst[n] * acc + ALPHA * h0[(size_t)n * OUT_SIZE + c];
        hout[(size_t)n * OUT_SIZE + c] = r;
    }
}

// ---------------- launcher ----------------
extern "C" void kernel_launch(void* const* d_in, const int* in_sizes, int n_in,
                              void* d_out, int out_size, void* d_ws, size_t ws_size,
                              hipStream_t stream) {
    const float* X   = (const float*)d_in[0];
    const int*   src = (const int*)d_in[1];
    const int*   dst = (const int*)d_in[2];
    const float* W1  = (const float*)d_in[3];
    const float* b1  = (const float*)d_in[4];
    const float* W2  = (const float*)d_in[5];
    const float* b2  = (const float*)d_in[6];
    float* out = (float*)d_out;

    char* ws = (char*)d_ws;
    size_t off = 0;
    auto alloc = [&](size_t bytes) -> void* {
        void* p = ws + off;
        off = (off + bytes + 255) & ~(size_t)255;
        return p;
    };
    // persistent across both phases
    float* h0 = (float*)alloc((size_t)N_NODES * OUT_SIZE * 4);     // 16 MB
    const size_t mark = off;

    // ---- phase A (MLP) region ----
    unsigned short* w1t = (unsigned short*)alloc((size_t)IN_SIZE * HID_SIZE * 2);  // 256 KB
    _Float16*       h1  = (_Float16*)alloc((size_t)N_NODES * HID_SIZE * 2);        // 51.2 MB

    // ---- phase B (propagation) region: ALIASES phase A (h1/w1t dead after gemm2) ----
    off = mark;
    float* hA   = (float*)alloc((size_t)N_NODES * OUT_SIZE * 4);
    float* hB   = (float*)alloc((size_t)N_NODES * OUT_SIZE * 4);
    float* nsrc = (float*)alloc((size_t)N_NODES * 4);
    float* ndst = (float*)alloc((size_t)N_NODES * 4);
    int* dego   = (int*)alloc((size_t)N_NODES * 4);
    int* degi   = (int*)alloc((size_t)N_NODES * 4);
    int* rowp   = (int*)alloc((size_t)(N_NODES + 1) * 4);
    int* cur    = (int*)alloc((size_t)N_NODES * 4);
    int* csr    = (int*)alloc((size_t)N_EDGES * 4);
    int* bsum   = (int*)alloc((size_t)SCAN_NB * 4);
    int* boff   = (int*)alloc((size_t)SCAN_NB * 4);

    const int egrid = (N_EDGES + 255) / 256;           // 6250
    const int ngrid = (N_NODES + 255) / 256;           // 391

    // ---- phase A: MLP first (so its scratch can be reused by CSR build) ----
    prep_w1t<<<(IN_SIZE * HID_SIZE + 255) / 256, 256, 0, stream>>>(W1, w1t);
    gemm1_f16<<<(N_NODES + 127) / 128, 512, 0, stream>>>(X, w1t, b1, h1);
    gemm2<<<(N_NODES + 63) / 64, 256, 0, stream>>>(h1, W2, b2, h0);

    // ---- phase B: CSR build ----
    hipMemsetAsync(dego, 0, (size_t)N_NODES * 4, stream);
    hipMemsetAsync(degi, 0, (size_t)N_NODES * 4, stream);
    degrees_kern<<<egrid, 256, 0, stream>>>(src, dst, dego, degi);
    norms_kern<<<ngrid, 256, 0, stream>>>(dego, degi, nsrc, ndst);
    scan_block_sums<<<SCAN_NB, 256, 0, stream>>>(degi, bsum);
    scan_offsets<<<1, 64, 0, stream>>>(bsum, boff);
    scan_write<<<SCAN_NB, 256, 0, stream>>>(degi, boff, rowp, cur);
    fill_csr<<<egrid, 256, 0, stream>>>(src, dst, cur, csr);

    // ---- propagation ----
    const float* hin = h0;
    const int sgrid = (N_NODES + 3) / 4;               // 25000
    for (int s = 0; s < K_STEPS; ++s) {
        float* hout = (s == K_STEPS - 1) ? out : ((s & 1) ? hB : hA);
        appnp_step<<<sgrid, 256, 0, stream>>>(hin, h0, rowp, csr, nsrc, ndst, hout);
        hin = hout;
    }
}

// Round 3
// 909.736 us; speedup vs baseline: 2.3242x; 1.6448x over previous
//
#include <hip/hip_runtime.h>

#define N_NODES 100000
#define N_EDGES 1600000
#define IN_SIZE 512
#define HID_SIZE 256
#define OUT_SIZE 40
#define K_STEPS 10
#define ALPHA 0.1f

#define SCAN_B 2048   // 256 threads * 8 elems
#define SCAN_NB ((N_NODES + SCAN_B - 1) / SCAN_B)   // 49

typedef _Float16 half8 __attribute__((ext_vector_type(8)));
typedef float f32x4 __attribute__((ext_vector_type(4)));

struct __align__(8) Entry { int s; float w; };

// ---------------- degree histogram ----------------
__global__ __launch_bounds__(256) void degrees_kern(const int* __restrict__ src,
                                                    const int* __restrict__ dst,
                                                    int* __restrict__ dego,
                                                    int* __restrict__ degi) {
    int i = blockIdx.x * 256 + threadIdx.x;
    if (i < N_EDGES) {
        atomicAdd(&dego[src[i]], 1);
        atomicAdd(&degi[dst[i]], 1);
    }
}

// ---------------- norms ----------------
__global__ __launch_bounds__(256) void norms_kern(const int* __restrict__ dego,
                                                  const int* __restrict__ degi,
                                                  float* __restrict__ nsrc,
                                                  float* __restrict__ ndst) {
    int i = blockIdx.x * 256 + threadIdx.x;
    if (i < N_NODES) {
        nsrc[i] = 1.0f / sqrtf((float)max(dego[i], 1));
        ndst[i] = 1.0f / sqrtf((float)max(degi[i], 1));
    }
}

// ---------------- scan (exclusive prefix over deg_in -> row_ptr) ----------------
__global__ __launch_bounds__(256) void scan_block_sums(const int* __restrict__ deg,
                                                       int* __restrict__ bsum) {
    __shared__ int s[256];
    int t = threadIdx.x, b = blockIdx.x;
    int base = b * SCAN_B + t * 8;
    int v = 0;
#pragma unroll
    for (int u = 0; u < 8; ++u) { int i = base + u; if (i < N_NODES) v += deg[i]; }
    s[t] = v; __syncthreads();
    for (int off = 128; off > 0; off >>= 1) {
        if (t < off) s[t] += s[t + off];
        __syncthreads();
    }
    if (t == 0) bsum[b] = s[0];
}

__global__ void scan_offsets(const int* __restrict__ bsum, int* __restrict__ boff) {
    if (threadIdx.x == 0 && blockIdx.x == 0) {
        int run = 0;
        for (int b = 0; b < SCAN_NB; ++b) { boff[b] = run; run += bsum[b]; }
    }
}

__global__ __launch_bounds__(256) void scan_write(const int* __restrict__ deg,
                                                  const int* __restrict__ boff,
                                                  int* __restrict__ row_ptr,
                                                  int* __restrict__ cursor) {
    __shared__ int s[256];
    int t = threadIdx.x, b = blockIdx.x;
    int base = b * SCAN_B + t * 8;
    int loc[8]; int tot = 0;
#pragma unroll
    for (int u = 0; u < 8; ++u) {
        int i = base + u;
        loc[u] = (i < N_NODES) ? deg[i] : 0;
        tot += loc[u];
    }
    s[t] = tot; __syncthreads();
    for (int off = 1; off < 256; off <<= 1) {
        int v = (t >= off) ? s[t - off] : 0;
        __syncthreads();
        s[t] += v;
        __syncthreads();
    }
    int run = boff[b] + s[t] - tot;
#pragma unroll
    for (int u = 0; u < 8; ++u) {
        int i = base + u;
        if (i < N_NODES) {
            row_ptr[i] = run;
            cursor[i]  = run;
            run += loc[u];
            if (i == N_NODES - 1) row_ptr[N_NODES] = run;
        }
    }
}

// ---------------- CSR fill: (src, prefolded weight) per edge ----------------
// w = (1-ALPHA) * nsrc[src] * ndst[dst]
__global__ __launch_bounds__(256) void fill_csr(const int* __restrict__ src,
                                                const int* __restrict__ dst,
                                                const float* __restrict__ nsrc,
                                                const float* __restrict__ ndst,
                                                int* __restrict__ cursor,
                                                Entry* __restrict__ csrw) {
    int i = blockIdx.x * 256 + threadIdx.x;
    if (i < N_EDGES) {
        int s = src[i];
        int d = dst[i];
        int pos = atomicAdd(&cursor[d], 1);
        Entry en;
        en.s = s;
        en.w = (1.0f - ALPHA) * nsrc[s] * ndst[d];
        csrw[pos] = en;
    }
}

// ---------------- prep: W1^T as fp16 [256][512] ----------------
__global__ __launch_bounds__(256) void prep_w1t(const float* __restrict__ W1,
                                                unsigned short* __restrict__ w1t) {
    int idx = blockIdx.x * 256 + threadIdx.x;   // 131072
    if (idx < IN_SIZE * HID_SIZE) {
        int n = idx >> 9;       // 0..255
        int k = idx & 511;      // 0..511
        _Float16 h = (_Float16)W1[(size_t)k * HID_SIZE + n];
        w1t[idx] = *(unsigned short*)&h;
    }
}

// ---------------- GEMM1: h1 = relu(X @ W1 + b1) in fp16 via MFMA ----------------
__global__ __launch_bounds__(512) void gemm1_f16(const float* __restrict__ X,
                                                 const unsigned short* __restrict__ w1t,
                                                 const float* __restrict__ b1,
                                                 _Float16* __restrict__ h1) {
    __shared__ __align__(16) _Float16 sA[128 * 64];
    __shared__ __align__(16) _Float16 sB[256 * 64];

    const int t    = threadIdx.x;
    const int lane = t & 63;
    const int w    = t >> 6;        // 0..7
    const int wr   = w >> 2;        // 0..1 : M
    const int wc   = w & 3;         // 0..3 : N
    const int n0   = blockIdx.x * 128;

    f32x4 acc[4][4];
#pragma unroll
    for (int i = 0; i < 4; ++i)
#pragma unroll
        for (int j = 0; j < 4; ++j) acc[i][j] = (f32x4)0.f;

    const int lo = lane & 15;
    const int hi = lane >> 4;
    const int l7 = lane & 7;

    for (int kk = 0; kk < IN_SIZE; kk += 64) {
        __syncthreads();
        // ---- stage A: X[128 rows][kk..kk+63] -> fp16, swizzled ----
#pragma unroll
        for (int i = 0; i < 2; ++i) {
            int id  = t + i * 512;          // 0..1023
            int row = id >> 3;              // 0..127
            int ch  = id & 7;               // 16B chunk (8 halves)
            int gr  = n0 + row;
            float4 x0 = make_float4(0.f, 0.f, 0.f, 0.f), x1 = x0;
            if (gr < N_NODES) {
                const float* p = X + (size_t)gr * IN_SIZE + kk + ch * 8;
                x0 = ((const float4*)p)[0];
                x1 = ((const float4*)p)[1];
            }
            half8 hv;
            hv[0] = (_Float16)x0.x; hv[1] = (_Float16)x0.y;
            hv[2] = (_Float16)x0.z; hv[3] = (_Float16)x0.w;
            hv[4] = (_Float16)x1.x; hv[5] = (_Float16)x1.y;
            hv[6] = (_Float16)x1.z; hv[7] = (_Float16)x1.w;
            *(half8*)&sA[row * 64 + ((ch ^ (row & 7)) << 3)] = hv;
        }
        // ---- stage B: W1^T[256 n][kk..kk+63] fp16, swizzled ----
#pragma unroll
        for (int i = 0; i < 4; ++i) {
            int id = t + i * 512;           // 0..2047
            int n  = id >> 3;               // 0..255
            int ch = id & 7;
            uint4 v = *(const uint4*)(w1t + (size_t)n * IN_SIZE + kk + ch * 8);
            *(uint4*)&sB[n * 64 + ((ch ^ (n & 7)) << 3)] = v;
        }
        __syncthreads();
        // ---- compute: 2 k-slices of 32 ----
#pragma unroll
        for (int s = 0; s < 2; ++s) {
            const int chs = ((s * 4 + hi) ^ l7) << 3;
            half8 af[4], bf[4];
#pragma unroll
            for (int f = 0; f < 4; ++f)
                af[f] = *(const half8*)&sA[(wr * 64 + f * 16 + lo) * 64 + chs];
#pragma unroll
            for (int f = 0; f < 4; ++f)
                bf[f] = *(const half8*)&sB[(wc * 64 + f * 16 + lo) * 64 + chs];
#pragma unroll
            for (int fi = 0; fi < 4; ++fi)
#pragma unroll
                for (int fj = 0; fj < 4; ++fj)
                    acc[fi][fj] = __builtin_amdgcn_mfma_f32_16x16x32_f16(
                        af[fi], bf[fj], acc[fi][fj], 0, 0, 0);
        }
    }

    // ---- epilogue: +b1, relu, fp16 store ----
    float b1v[4];
#pragma unroll
    for (int fj = 0; fj < 4; ++fj) b1v[fj] = b1[wc * 64 + fj * 16 + lo];
#pragma unroll
    for (int fi = 0; fi < 4; ++fi) {
#pragma unroll
        for (int fj = 0; fj < 4; ++fj) {
            const int col = wc * 64 + fj * 16 + lo;
#pragma unroll
            for (int r = 0; r < 4; ++r) {
                int grow = n0 + wr * 64 + fi * 16 + hi * 4 + r;
                if (grow < N_NODES) {
                    float v = acc[fi][fj][r] + b1v[fj];
                    v = fmaxf(v, 0.f);
                    h1[(size_t)grow * HID_SIZE + col] = (_Float16)v;
                }
            }
        }
    }
}

// ---------------- GEMM2: h0 = h1 @ W2 + b2 (fp32 accumulate) ----------------
__global__ __launch_bounds__(256) void gemm2(const _Float16* __restrict__ h1,
                                             const float* __restrict__ W2,
                                             const float* __restrict__ b2,
                                             float* __restrict__ h0) {
    __shared__ __align__(16) float sW2t[40 * 260];
    __shared__ __align__(16) unsigned short sH[64 * 264];

    const int t  = threadIdx.x;
    const int n0 = blockIdx.x * 64;

    for (int idx = t; idx < HID_SIZE * OUT_SIZE; idx += 256) {
        int c = idx / OUT_SIZE;
        int o = idx - c * OUT_SIZE;
        sW2t[o * 260 + c] = W2[idx];
    }
#pragma unroll
    for (int i = 0; i < 8; ++i) {
        int id  = t + i * 256;          // 0..2047
        int row = id >> 5;              // 0..63
        int ch  = id & 31;              // 16B chunks of 8 halves
        uint4 v = make_uint4(0, 0, 0, 0);
        if (n0 + row < N_NODES)
            v = *(const uint4*)(h1 + (size_t)(n0 + row) * HID_SIZE + ch * 8);
        *(uint4*)&sH[row * 264 + ch * 8] = v;
    }
    __syncthreads();

    const int r2 = t >> 2;
    const int q  = t & 3;
    const int o0 = q * 10;
    float acc2[10];
#pragma unroll
    for (int m = 0; m < 10; ++m) acc2[m] = b2[o0 + m];

    for (int c = 0; c < HID_SIZE; c += 8) {
        uint4 hv = *(const uint4*)&sH[r2 * 264 + c];
        const _Float16* hp = (const _Float16*)&hv;
        float f[8];
#pragma unroll
        for (int j = 0; j < 8; ++j) f[j] = (float)hp[j];
#pragma unroll
        for (int m = 0; m < 10; ++m) {
            const float4 w0 = *(const float4*)&sW2t[(o0 + m) * 260 + c];
            const float4 w1 = *(const float4*)&sW2t[(o0 + m) * 260 + c + 4];
            acc2[m] += f[0] * w0.x + f[1] * w0.y + f[2] * w0.z + f[3] * w0.w
                     + f[4] * w1.x + f[5] * w1.y + f[6] * w1.z + f[7] * w1.w;
        }
    }
    if (n0 + r2 < N_NODES) {
        float* dstp = h0 + (size_t)(n0 + r2) * OUT_SIZE + o0;
#pragma unroll
        for (int m = 0; m < 10; ++m) dstp[m] = acc2[m];
    }
}

// ---------------- APPNP step v2: thread = (node, float4-quad of channels) ----
// 320 threads/block = 32 nodes * 10 quads. 3125 blocks = exactly 100000 nodes.
// Per thread: loop node's CSR edges, unroll x4 -> 4 entry loads + 4 float4
// gathers in flight; no cross-lane ops. w prefolds (1-a)*nsrc*ndst.
__global__ __launch_bounds__(320) void appnp_step2(const float* __restrict__ hin,
                                                   const float* __restrict__ h0,
                                                   const int* __restrict__ rowp,
                                                   const Entry* __restrict__ csrw,
                                                   float* __restrict__ hout) {
    const int tid = threadIdx.x;
    const int ln  = tid / 10;
    const int q   = tid - ln * 10;
    const int n   = blockIdx.x * 32 + ln;

    const int beg = rowp[n];
    const int end = rowp[n + 1];

    f32x4 acc = (f32x4)0.f;
    int e = beg;
    for (; e + 4 <= end; e += 4) {
        const Entry e0 = csrw[e + 0];
        const Entry e1 = csrw[e + 1];
        const Entry e2 = csrw[e + 2];
        const Entry e3 = csrw[e + 3];
        const f32x4 v0 = *(const f32x4*)(hin + (size_t)e0.s * OUT_SIZE + q * 4);
        const f32x4 v1 = *(const f32x4*)(hin + (size_t)e1.s * OUT_SIZE + q * 4);
        const f32x4 v2 = *(const f32x4*)(hin + (size_t)e2.s * OUT_SIZE + q * 4);
        const f32x4 v3 = *(const f32x4*)(hin + (size_t)e3.s * OUT_SIZE + q * 4);
        acc += v0 * e0.w;
        acc += v1 * e1.w;
        acc += v2 * e2.w;
        acc += v3 * e3.w;
    }
    if (e + 2 <= end) {
        const Entry e0 = csrw[e + 0];
        const Entry e1 = csrw[e + 1];
        const f32x4 v0 = *(const f32x4*)(hin + (size_t)e0.s * OUT_SIZE + q * 4);
        const f32x4 v1 = *(const f32x4*)(hin + (size_t)e1.s * OUT_SIZE + q * 4);
        acc += v0 * e0.w;
        acc += v1 * e1.w;
        e += 2;
    }
    if (e < end) {
        const Entry e0 = csrw[e];
        const f32x4 v0 = *(const f32x4*)(hin + (size_t)e0.s * OUT_SIZE + q * 4);
        acc += v0 * e0.w;
    }

    const f32x4 h04 = *(const f32x4*)(h0 + (size_t)n * OUT_SIZE + q * 4);
    const f32x4 r = acc + ALPHA * h04;
    *(f32x4*)(hout + (size_t)n * OUT_SIZE + q * 4) = r;
}

// ---------------- launcher ----------------
extern "C" void kernel_launch(void* const* d_in, const int* in_sizes, int n_in,
                              void* d_out, int out_size, void* d_ws, size_t ws_size,
                              hipStream_t stream) {
    const float* X   = (const float*)d_in[0];
    const int*   src = (const int*)d_in[1];
    const int*   dst = (const int*)d_in[2];
    const float* W1  = (const float*)d_in[3];
    const float* b1  = (const float*)d_in[4];
    const float* W2  = (const float*)d_in[5];
    const float* b2  = (const float*)d_in[6];
    float* out = (float*)d_out;

    char* ws = (char*)d_ws;
    size_t off = 0;
    auto alloc = [&](size_t bytes) -> void* {
        void* p = ws + off;
        off = (off + bytes + 255) & ~(size_t)255;
        return p;
    };
    // persistent
    float* h0 = (float*)alloc((size_t)N_NODES * OUT_SIZE * 4);     // 16 MB
    const size_t mark = off;

    // ---- phase A (MLP) region ----
    unsigned short* w1t = (unsigned short*)alloc((size_t)IN_SIZE * HID_SIZE * 2);  // 256 KB
    _Float16*       h1  = (_Float16*)alloc((size_t)N_NODES * HID_SIZE * 2);        // 51.2 MB

    // ---- phase B (propagation) region: ALIASES phase A (h1/w1t dead after gemm2) ----
    off = mark;
    float* hA   = (float*)alloc((size_t)N_NODES * OUT_SIZE * 4);
    float* hB   = (float*)alloc((size_t)N_NODES * OUT_SIZE * 4);
    float* nsrc = (float*)alloc((size_t)N_NODES * 4);
    float* ndst = (float*)alloc((size_t)N_NODES * 4);
    int* dego   = (int*)alloc((size_t)N_NODES * 4);
    int* degi   = (int*)alloc((size_t)N_NODES * 4);
    int* rowp   = (int*)alloc((size_t)(N_NODES + 1) * 4);
    int* cur    = (int*)alloc((size_t)N_NODES * 4);
    Entry* csrw = (Entry*)alloc((size_t)N_EDGES * 8);
    int* bsum   = (int*)alloc((size_t)SCAN_NB * 4);
    int* boff   = (int*)alloc((size_t)SCAN_NB * 4);

    const int egrid = (N_EDGES + 255) / 256;           // 6250
    const int ngrid = (N_NODES + 255) / 256;           // 391

    // ---- phase A: MLP first (its scratch is reused by the CSR build) ----
    prep_w1t<<<(IN_SIZE * HID_SIZE + 255) / 256, 256, 0, stream>>>(W1, w1t);
    gemm1_f16<<<(N_NODES + 127) / 128, 512, 0, stream>>>(X, w1t, b1, h1);
    gemm2<<<(N_NODES + 63) / 64, 256, 0, stream>>>(h1, W2, b2, h0);

    // ---- phase B: CSR build ----
    hipMemsetAsync(dego, 0, (size_t)N_NODES * 4, stream);
    hipMemsetAsync(degi, 0, (size_t)N_NODES * 4, stream);
    degrees_kern<<<egrid, 256, 0, stream>>>(src, dst, dego, degi);
    norms_kern<<<ngrid, 256, 0, stream>>>(dego, degi, nsrc, ndst);
    scan_block_sums<<<SCAN_NB, 256, 0, stream>>>(degi, bsum);
    scan_offsets<<<1, 64, 0, stream>>>(bsum, boff);
    scan_write<<<SCAN_NB, 256, 0, stream>>>(degi, boff, rowp, cur);
    fill_csr<<<egrid, 256, 0, stream>>>(src, dst, nsrc, ndst, cur, csrw);

    // ---- propagation ----
    const float* hin = h0;
    for (int s = 0; s < K_STEPS; ++s) {
        float* hout = (s == K_STEPS - 1) ? out : ((s & 1) ? hB : hA);
        appnp_step2<<<3125, 320, 0, stream>>>(hin, h0, rowp, csrw, hout);
        hin = hout;
    }
}

// Round 4
// 738.952 us; speedup vs baseline: 2.8613x; 1.2311x over previous
//
#include <hip/hip_runtime.h>

#define N_NODES 100000
#define N_EDGES 1600000
#define IN_SIZE 512
#define HID_SIZE 256
#define OUT_SIZE 40
#define K_STEPS 10
#define ALPHA 0.1f

#define SCAN_B 2048   // 256 threads * 8 elems
#define SCAN_NB ((N_NODES + SCAN_B - 1) / SCAN_B)   // 49

typedef _Float16 half8 __attribute__((ext_vector_type(8)));
typedef float f32x4 __attribute__((ext_vector_type(4)));

// ---------------- degree histogram ----------------
__global__ __launch_bounds__(256) void degrees_kern(const int* __restrict__ src,
                                                    const int* __restrict__ dst,
                                                    int* __restrict__ dego,
                                                    int* __restrict__ degi) {
    int i = blockIdx.x * 256 + threadIdx.x;
    if (i < N_EDGES) {
        atomicAdd(&dego[src[i]], 1);
        atomicAdd(&degi[dst[i]], 1);
    }
}

// ---------------- norms ----------------
__global__ __launch_bounds__(256) void norms_kern(const int* __restrict__ dego,
                                                  const int* __restrict__ degi,
                                                  float* __restrict__ nsrc,
                                                  float* __restrict__ ndst) {
    int i = blockIdx.x * 256 + threadIdx.x;
    if (i < N_NODES) {
        nsrc[i] = 1.0f / sqrtf((float)max(dego[i], 1));
        ndst[i] = 1.0f / sqrtf((float)max(degi[i], 1));
    }
}

// ---------------- scan (exclusive prefix over deg_in -> row_ptr) ----------------
__global__ __launch_bounds__(256) void scan_block_sums(const int* __restrict__ deg,
                                                       int* __restrict__ bsum) {
    __shared__ int s[256];
    int t = threadIdx.x, b = blockIdx.x;
    int base = b * SCAN_B + t * 8;
    int v = 0;
#pragma unroll
    for (int u = 0; u < 8; ++u) { int i = base + u; if (i < N_NODES) v += deg[i]; }
    s[t] = v; __syncthreads();
    for (int off = 128; off > 0; off >>= 1) {
        if (t < off) s[t] += s[t + off];
        __syncthreads();
    }
    if (t == 0) bsum[b] = s[0];
}

__global__ void scan_offsets(const int* __restrict__ bsum, int* __restrict__ boff) {
    if (threadIdx.x == 0 && blockIdx.x == 0) {
        int run = 0;
        for (int b = 0; b < SCAN_NB; ++b) { boff[b] = run; run += bsum[b]; }
    }
}

__global__ __launch_bounds__(256) void scan_write(const int* __restrict__ deg,
                                                  const int* __restrict__ boff,
                                                  int* __restrict__ row_ptr,
                                                  int* __restrict__ cursor) {
    __shared__ int s[256];
    int t = threadIdx.x, b = blockIdx.x;
    int base = b * SCAN_B + t * 8;
    int loc[8]; int tot = 0;
#pragma unroll
    for (int u = 0; u < 8; ++u) {
        int i = base + u;
        loc[u] = (i < N_NODES) ? deg[i] : 0;
        tot += loc[u];
    }
    s[t] = tot; __syncthreads();
    for (int off = 1; off < 256; off <<= 1) {
        int v = (t >= off) ? s[t - off] : 0;
        __syncthreads();
        s[t] += v;
        __syncthreads();
    }
    int run = boff[b] + s[t] - tot;
#pragma unroll
    for (int u = 0; u < 8; ++u) {
        int i = base + u;
        if (i < N_NODES) {
            row_ptr[i] = run;
            cursor[i]  = run;
            run += loc[u];
            if (i == N_NODES - 1) row_ptr[N_NODES] = run;
        }
    }
}

// ---------------- CSR fill: src index only (4B/edge) ----------------
__global__ __launch_bounds__(256) void fill_csr(const int* __restrict__ src,
                                                const int* __restrict__ dst,
                                                int* __restrict__ cursor,
                                                int* __restrict__ csr) {
    int i = blockIdx.x * 256 + threadIdx.x;
    if (i < N_EDGES) {
        int s = src[i];
        int d = dst[i];
        int pos = atomicAdd(&cursor[d], 1);
        csr[pos] = s;
    }
}

// ---------------- prep: W1^T as fp16 [256][512] ----------------
__global__ __launch_bounds__(256) void prep_w1t(const float* __restrict__ W1,
                                                unsigned short* __restrict__ w1t) {
    int idx = blockIdx.x * 256 + threadIdx.x;   // 131072
    if (idx < IN_SIZE * HID_SIZE) {
        int n = idx >> 9;       // 0..255
        int k = idx & 511;      // 0..511
        _Float16 h = (_Float16)W1[(size_t)k * HID_SIZE + n];
        w1t[idx] = *(unsigned short*)&h;
    }
}

// ---------------- GEMM1: h1 = relu(X @ W1 + b1) in fp16 via MFMA ----------------
__global__ __launch_bounds__(512) void gemm1_f16(const float* __restrict__ X,
                                                 const unsigned short* __restrict__ w1t,
                                                 const float* __restrict__ b1,
                                                 _Float16* __restrict__ h1) {
    __shared__ __align__(16) _Float16 sA[128 * 64];
    __shared__ __align__(16) _Float16 sB[256 * 64];

    const int t    = threadIdx.x;
    const int lane = t & 63;
    const int w    = t >> 6;        // 0..7
    const int wr   = w >> 2;        // 0..1 : M
    const int wc   = w & 3;         // 0..3 : N
    const int n0   = blockIdx.x * 128;

    f32x4 acc[4][4];
#pragma unroll
    for (int i = 0; i < 4; ++i)
#pragma unroll
        for (int j = 0; j < 4; ++j) acc[i][j] = (f32x4)0.f;

    const int lo = lane & 15;
    const int hi = lane >> 4;
    const int l7 = lane & 7;

    for (int kk = 0; kk < IN_SIZE; kk += 64) {
        __syncthreads();
        // ---- stage A: X[128 rows][kk..kk+63] -> fp16, swizzled ----
#pragma unroll
        for (int i = 0; i < 2; ++i) {
            int id  = t + i * 512;          // 0..1023
            int row = id >> 3;              // 0..127
            int ch  = id & 7;               // 16B chunk (8 halves)
            int gr  = n0 + row;
            float4 x0 = make_float4(0.f, 0.f, 0.f, 0.f), x1 = x0;
            if (gr < N_NODES) {
                const float* p = X + (size_t)gr * IN_SIZE + kk + ch * 8;
                x0 = ((const float4*)p)[0];
                x1 = ((const float4*)p)[1];
            }
            half8 hv;
            hv[0] = (_Float16)x0.x; hv[1] = (_Float16)x0.y;
            hv[2] = (_Float16)x0.z; hv[3] = (_Float16)x0.w;
            hv[4] = (_Float16)x1.x; hv[5] = (_Float16)x1.y;
            hv[6] = (_Float16)x1.z; hv[7] = (_Float16)x1.w;
            *(half8*)&sA[row * 64 + ((ch ^ (row & 7)) << 3)] = hv;
        }
        // ---- stage B: W1^T[256 n][kk..kk+63] fp16, swizzled ----
#pragma unroll
        for (int i = 0; i < 4; ++i) {
            int id = t + i * 512;           // 0..2047
            int n  = id >> 3;               // 0..255
            int ch = id & 7;
            uint4 v = *(const uint4*)(w1t + (size_t)n * IN_SIZE + kk + ch * 8);
            *(uint4*)&sB[n * 64 + ((ch ^ (n & 7)) << 3)] = v;
        }
        __syncthreads();
        // ---- compute: 2 k-slices of 32 ----
#pragma unroll
        for (int s = 0; s < 2; ++s) {
            const int chs = ((s * 4 + hi) ^ l7) << 3;
            half8 af[4], bf[4];
#pragma unroll
            for (int f = 0; f < 4; ++f)
                af[f] = *(const half8*)&sA[(wr * 64 + f * 16 + lo) * 64 + chs];
#pragma unroll
            for (int f = 0; f < 4; ++f)
                bf[f] = *(const half8*)&sB[(wc * 64 + f * 16 + lo) * 64 + chs];
#pragma unroll
            for (int fi = 0; fi < 4; ++fi)
#pragma unroll
                for (int fj = 0; fj < 4; ++fj)
                    acc[fi][fj] = __builtin_amdgcn_mfma_f32_16x16x32_f16(
                        af[fi], bf[fj], acc[fi][fj], 0, 0, 0);
        }
    }

    // ---- epilogue: +b1, relu, fp16 store ----
    float b1v[4];
#pragma unroll
    for (int fj = 0; fj < 4; ++fj) b1v[fj] = b1[wc * 64 + fj * 16 + lo];
#pragma unroll
    for (int fi = 0; fi < 4; ++fi) {
#pragma unroll
        for (int fj = 0; fj < 4; ++fj) {
            const int col = wc * 64 + fj * 16 + lo;
#pragma unroll
            for (int r = 0; r < 4; ++r) {
                int grow = n0 + wr * 64 + fi * 16 + hi * 4 + r;
                if (grow < N_NODES) {
                    float v = acc[fi][fj][r] + b1v[fj];
                    v = fmaxf(v, 0.f);
                    h1[(size_t)grow * HID_SIZE + col] = (_Float16)v;
                }
            }
        }
    }
}

// ---------------- GEMM2: h0 = h1 @ W2 + b2 (fp32 accumulate) ----------------
__global__ __launch_bounds__(256) void gemm2(const _Float16* __restrict__ h1,
                                             const float* __restrict__ W2,
                                             const float* __restrict__ b2,
                                             float* __restrict__ h0) {
    __shared__ __align__(16) float sW2t[40 * 260];
    __shared__ __align__(16) unsigned short sH[64 * 264];

    const int t  = threadIdx.x;
    const int n0 = blockIdx.x * 64;

    for (int idx = t; idx < HID_SIZE * OUT_SIZE; idx += 256) {
        int c = idx / OUT_SIZE;
        int o = idx - c * OUT_SIZE;
        sW2t[o * 260 + c] = W2[idx];
    }
#pragma unroll
    for (int i = 0; i < 8; ++i) {
        int id  = t + i * 256;          // 0..2047
        int row = id >> 5;              // 0..63
        int ch  = id & 31;              // 16B chunks of 8 halves
        uint4 v = make_uint4(0, 0, 0, 0);
        if (n0 + row < N_NODES)
            v = *(const uint4*)(h1 + (size_t)(n0 + row) * HID_SIZE + ch * 8);
        *(uint4*)&sH[row * 264 + ch * 8] = v;
    }
    __syncthreads();

    const int r2 = t >> 2;
    const int q  = t & 3;
    const int o0 = q * 10;
    float acc2[10];
#pragma unroll
    for (int m = 0; m < 10; ++m) acc2[m] = b2[o0 + m];

    for (int c = 0; c < HID_SIZE; c += 8) {
        uint4 hv = *(const uint4*)&sH[r2 * 264 + c];
        const _Float16* hp = (const _Float16*)&hv;
        float f[8];
#pragma unroll
        for (int j = 0; j < 8; ++j) f[j] = (float)hp[j];
#pragma unroll
        for (int m = 0; m < 10; ++m) {
            const float4 w0 = *(const float4*)&sW2t[(o0 + m) * 260 + c];
            const float4 w1 = *(const float4*)&sW2t[(o0 + m) * 260 + c + 4];
            acc2[m] += f[0] * w0.x + f[1] * w0.y + f[2] * w0.z + f[3] * w0.w
                     + f[4] * w1.x + f[5] * w1.y + f[6] * w1.z + f[7] * w1.w;
        }
    }
    if (n0 + r2 < N_NODES) {
        float* dstp = h0 + (size_t)(n0 + r2) * OUT_SIZE + o0;
#pragma unroll
        for (int m = 0; m < 10; ++m) dstp[m] = acc2[m];
    }
}

// ---------------- g0 = nsrc * h0, fp16, rows padded to 64 halves (128B) ------
__global__ __launch_bounds__(320) void g0_init(const float* __restrict__ h0,
                                               const float* __restrict__ nsrc,
                                               _Float16* __restrict__ g) {
    const int tid = threadIdx.x;
    const int ln  = tid / 5;
    const int q   = tid - ln * 5;
    const int n   = blockIdx.x * 64 + ln;
    if (n >= N_NODES) return;
    const float ns = nsrc[n];
    const f32x4 a = *(const f32x4*)(h0 + (size_t)n * OUT_SIZE + q * 8);
    const f32x4 b = *(const f32x4*)(h0 + (size_t)n * OUT_SIZE + q * 8 + 4);
    half8 gv;
    gv[0] = (_Float16)(ns * a[0]); gv[1] = (_Float16)(ns * a[1]);
    gv[2] = (_Float16)(ns * a[2]); gv[3] = (_Float16)(ns * a[3]);
    gv[4] = (_Float16)(ns * b[0]); gv[5] = (_Float16)(ns * b[1]);
    gv[6] = (_Float16)(ns * b[2]); gv[7] = (_Float16)(ns * b[3]);
    *(half8*)(g + (size_t)n * 64 + q * 8) = gv;
}

// ---------------- APPNP step v3: scaled fp16 state, unweighted gather --------
// g_t = nsrc ⊙ h_t  (rows padded to 64 halves = 128B, exactly 2 cache lines).
// 5 threads/node (half8 each), block 320 = 64 nodes.
// h' = (1-a)*ndst[n]*Σ g[s] + a*h0[n];   g' = nsrc[n]*h'  (or out=h' on last).
__global__ __launch_bounds__(320) void appnp_step3(const _Float16* __restrict__ gin,
                                                   const float* __restrict__ h0,
                                                   const int* __restrict__ rowp,
                                                   const int* __restrict__ csr,
                                                   const float* __restrict__ nsrc,
                                                   const float* __restrict__ ndst,
                                                   _Float16* __restrict__ gout,
                                                   float* __restrict__ hout,
                                                   int last) {
    const int tid = threadIdx.x;
    const int ln  = tid / 5;
    const int q   = tid - ln * 5;
    const int n   = blockIdx.x * 64 + ln;
    if (n >= N_NODES) return;

    const int beg = rowp[n];
    const int end = rowp[n + 1];
    const _Float16* gq = gin + q * 8;

    float acc[8];
#pragma unroll
    for (int j = 0; j < 8; ++j) acc[j] = 0.f;

    int e = beg;
    for (; e + 4 <= end; e += 4) {
        const int s0 = csr[e + 0];
        const int s1 = csr[e + 1];
        const int s2 = csr[e + 2];
        const int s3 = csr[e + 3];
        const half8 v0 = *(const half8*)(gq + (size_t)s0 * 64);
        const half8 v1 = *(const half8*)(gq + (size_t)s1 * 64);
        const half8 v2 = *(const half8*)(gq + (size_t)s2 * 64);
        const half8 v3 = *(const half8*)(gq + (size_t)s3 * 64);
#pragma unroll
        for (int j = 0; j < 8; ++j)
            acc[j] += (float)v0[j] + (float)v1[j] + (float)v2[j] + (float)v3[j];
    }
    for (; e < end; ++e) {
        const int s0 = csr[e];
        const half8 v0 = *(const half8*)(gq + (size_t)s0 * 64);
#pragma unroll
        for (int j = 0; j < 8; ++j) acc[j] += (float)v0[j];
    }

    const float nd = (1.0f - ALPHA) * ndst[n];
    const f32x4 h0a = *(const f32x4*)(h0 + (size_t)n * OUT_SIZE + q * 8);
    const f32x4 h0b = *(const f32x4*)(h0 + (size_t)n * OUT_SIZE + q * 8 + 4);
    float r[8];
    r[0] = nd * acc[0] + ALPHA * h0a[0]; r[1] = nd * acc[1] + ALPHA * h0a[1];
    r[2] = nd * acc[2] + ALPHA * h0a[2]; r[3] = nd * acc[3] + ALPHA * h0a[3];
    r[4] = nd * acc[4] + ALPHA * h0b[0]; r[5] = nd * acc[5] + ALPHA * h0b[1];
    r[6] = nd * acc[6] + ALPHA * h0b[2]; r[7] = nd * acc[7] + ALPHA * h0b[3];

    if (last) {
        f32x4 ra, rb;
        ra[0] = r[0]; ra[1] = r[1]; ra[2] = r[2]; ra[3] = r[3];
        rb[0] = r[4]; rb[1] = r[5]; rb[2] = r[6]; rb[3] = r[7];
        *(f32x4*)(hout + (size_t)n * OUT_SIZE + q * 8) = ra;
        *(f32x4*)(hout + (size_t)n * OUT_SIZE + q * 8 + 4) = rb;
    } else {
        const float ns = nsrc[n];
        half8 gv;
#pragma unroll
        for (int j = 0; j < 8; ++j) gv[j] = (_Float16)(ns * r[j]);
        *(half8*)(gout + (size_t)n * 64 + q * 8) = gv;
    }
}

// ---------------- launcher ----------------
extern "C" void kernel_launch(void* const* d_in, const int* in_sizes, int n_in,
                              void* d_out, int out_size, void* d_ws, size_t ws_size,
                              hipStream_t stream) {
    const float* X   = (const float*)d_in[0];
    const int*   src = (const int*)d_in[1];
    const int*   dst = (const int*)d_in[2];
    const float* W1  = (const float*)d_in[3];
    const float* b1  = (const float*)d_in[4];
    const float* W2  = (const float*)d_in[5];
    const float* b2  = (const float*)d_in[6];
    float* out = (float*)d_out;

    char* ws = (char*)d_ws;
    size_t off = 0;
    auto alloc = [&](size_t bytes) -> void* {
        void* p = ws + off;
        off = (off + bytes + 255) & ~(size_t)255;
        return p;
    };
    // persistent
    float* h0 = (float*)alloc((size_t)N_NODES * OUT_SIZE * 4);     // 16 MB
    const size_t mark = off;

    // ---- phase A (MLP) region ----
    unsigned short* w1t = (unsigned short*)alloc((size_t)IN_SIZE * HID_SIZE * 2);  // 256 KB
    _Float16*       h1  = (_Float16*)alloc((size_t)N_NODES * HID_SIZE * 2);        // 51.2 MB

    // ---- phase B region: ALIASES phase A (w1t/h1 dead after gemm2) ----
    off = mark;
    _Float16* gA = (_Float16*)alloc((size_t)N_NODES * 64 * 2);   // 12.8 MB
    _Float16* gB = (_Float16*)alloc((size_t)N_NODES * 64 * 2);   // 12.8 MB
    float* nsrc = (float*)alloc((size_t)N_NODES * 4);
    float* ndst = (float*)alloc((size_t)N_NODES * 4);
    int* dego   = (int*)alloc((size_t)N_NODES * 4);
    int* degi   = (int*)alloc((size_t)N_NODES * 4);
    int* rowp   = (int*)alloc((size_t)(N_NODES + 1) * 4);
    int* cur    = (int*)alloc((size_t)N_NODES * 4);
    int* csr    = (int*)alloc((size_t)N_EDGES * 4);              // 6.4 MB
    int* bsum   = (int*)alloc((size_t)SCAN_NB * 4);
    int* boff   = (int*)alloc((size_t)SCAN_NB * 4);

    const int egrid = (N_EDGES + 255) / 256;           // 6250
    const int ngrid = (N_NODES + 255) / 256;           // 391
    const int pgrid = (N_NODES + 63) / 64;             // 1563 (320-thread blocks)

    // ---- phase A: MLP first (its scratch is aliased by phase B buffers) ----
    prep_w1t<<<(IN_SIZE * HID_SIZE + 255) / 256, 256, 0, stream>>>(W1, w1t);
    gemm1_f16<<<(N_NODES + 127) / 128, 512, 0, stream>>>(X, w1t, b1, h1);
    gemm2<<<(N_NODES + 63) / 64, 256, 0, stream>>>(h1, W2, b2, h0);

    // ---- phase B: CSR build (after gemm2 -> h1/w1t dead, aliasing safe) ----
    hipMemsetAsync(dego, 0, (size_t)N_NODES * 4, stream);
    hipMemsetAsync(degi, 0, (size_t)N_NODES * 4, stream);
    degrees_kern<<<egrid, 256, 0, stream>>>(src, dst, dego, degi);
    norms_kern<<<ngrid, 256, 0, stream>>>(dego, degi, nsrc, ndst);
    scan_block_sums<<<SCAN_NB, 256, 0, stream>>>(degi, bsum);
    scan_offsets<<<1, 64, 0, stream>>>(bsum, boff);
    scan_write<<<SCAN_NB, 256, 0, stream>>>(degi, boff, rowp, cur);
    fill_csr<<<egrid, 256, 0, stream>>>(src, dst, cur, csr);

    // ---- scaled initial state ----
    g0_init<<<pgrid, 320, 0, stream>>>(h0, nsrc, gA);

    // ---- propagation ----
    const _Float16* gin = gA;
    for (int s = 0; s < K_STEPS; ++s) {
        const int last = (s == K_STEPS - 1) ? 1 : 0;
        _Float16* gout = (s & 1) ? gA : gB;
        appnp_step3<<<pgrid, 320, 0, stream>>>(gin, h0, rowp, csr, nsrc, ndst,
                                               gout, out, last);
        gin = gout;
    }
}